// Round 3
// baseline (317.863 us; speedup 1.0000x reference)
//
#include <hip/hip_runtime.h>
#include <hip/hip_bf16.h>
#include <cstdint>

// out[M,N] = x[M,K] @ weight[N,K]^T, fp32 device buffers (fp16 reference ->
// harness float32 path). Single fused kernel: fp32 global -> reg -> cvt bf16
// -> double-buffered LDS -> 16x16x32 bf16 MFMA -> fp32 C. No d_ws usage, no
// multi-dispatch dependency (Round-2 post-timing divergence eliminator).

typedef __bf16 bf16x8 __attribute__((ext_vector_type(8)));
typedef float f32x4 __attribute__((ext_vector_type(4)));
typedef unsigned short u16x8 __attribute__((ext_vector_type(8)));

__device__ inline unsigned short f2bf(float f) {
    __hip_bfloat16 h = __float2bfloat16(f);  // RNE
    return *reinterpret_cast<unsigned short*>(&h);
}

__global__ __launch_bounds__(256) void gemm_bt_fused(
    const float* __restrict__ A,   // x      [M,K]
    const float* __restrict__ B,   // weight [N,K]
    float* __restrict__ C,         // out    [M,N]
    int M, int N, int K)
{
    constexpr int BM = 128, BN = 128, BK = 32;
    __shared__ unsigned short sA[2][BM * BK];  // 2 x 8 KB
    __shared__ unsigned short sB[2][BN * BK];  // 2 x 8 KB

    const int nbn = N / BN;
    const int nwg = (M / BM) * nbn;
    const int bid = blockIdx.x;
    int swz = bid;
    if ((nwg & 7) == 0) {                       // bijective XCD swizzle
        const int q = nwg >> 3;
        swz = (bid & 7) * q + (bid >> 3);
    }
    const int bm = swz / nbn;
    const int bn = swz % nbn;

    const int tid = threadIdx.x;

    // ---- staging map: thread covers 16 contiguous floats of one tile row
    const int srow = tid >> 1;           // 0..127
    const int scol = (tid & 1) * 16;     // 0 or 16
    const float* gA = A + (size_t)(bm * BM + srow) * K + scol;
    const float* gB = B + (size_t)(bn * BN + srow) * K + scol;
    const int woff = srow * BK + scol;   // LDS short-offset (16B-aligned)

    // ---- fragment geometry: wave (wr,wc) owns 64x64, acc[4][4] of 16x16
    const int wave = tid >> 6, lane = tid & 63;
    const int wr = wave >> 1, wc = wave & 1;
    const int fr = lane & 15;
    const int fk = (lane >> 4) * 8;
    int offA[4], offB[4];
#pragma unroll
    for (int i = 0; i < 4; ++i) {
        offA[i] = (wr * 64 + i * 16 + fr) * BK + fk;
        offB[i] = (wc * 64 + i * 16 + fr) * BK + fk;
    }

    f32x4 acc[4][4] = {};

    const int NT = K / BK;               // 128

    // ---- prologue: load tile 0 into registers
    float4 va[4], vb[4];
#pragma unroll
    for (int p = 0; p < 4; ++p) {
        va[p] = *reinterpret_cast<const float4*>(gA + p * 4);
        vb[p] = *reinterpret_cast<const float4*>(gB + p * 4);
    }

    for (int t = 0; t < NT; ++t) {
        const int cur = t & 1;

        // convert current tile regs -> bf16, write to LDS buf[cur]
        u16x8 pa0, pa1, pb0, pb1;
#pragma unroll
        for (int e = 0; e < 4; ++e) {
            pa0[e]     = f2bf(va[0][e]);  pa0[4 + e] = f2bf(va[1][e]);
            pa1[e]     = f2bf(va[2][e]);  pa1[4 + e] = f2bf(va[3][e]);
            pb0[e]     = f2bf(vb[0][e]);  pb0[4 + e] = f2bf(vb[1][e]);
            pb1[e]     = f2bf(vb[2][e]);  pb1[4 + e] = f2bf(vb[3][e]);
        }
        *reinterpret_cast<u16x8*>(&sA[cur][woff])     = pa0;
        *reinterpret_cast<u16x8*>(&sA[cur][woff + 8]) = pa1;
        *reinterpret_cast<u16x8*>(&sB[cur][woff])     = pb0;
        *reinterpret_cast<u16x8*>(&sB[cur][woff + 8]) = pb1;

        // prefetch tile t+1 (clamped on last iter; redundant reload, harmless)
        const int kn = (t + 1 < NT) ? (t + 1) * BK : t * BK;
#pragma unroll
        for (int p = 0; p < 4; ++p) {
            va[p] = *reinterpret_cast<const float4*>(gA + kn + p * 4);
            vb[p] = *reinterpret_cast<const float4*>(gB + kn + p * 4);
        }

        __syncthreads();  // buf[cur] writes drained (lgkmcnt) + all waves arrived

        bf16x8 a[4], b[4];
#pragma unroll
        for (int i = 0; i < 4; ++i) a[i] = *reinterpret_cast<const bf16x8*>(&sA[cur][offA[i]]);
#pragma unroll
        for (int j = 0; j < 4; ++j) b[j] = *reinterpret_cast<const bf16x8*>(&sB[cur][offB[j]]);
#pragma unroll
        for (int i = 0; i < 4; ++i)
#pragma unroll
            for (int j = 0; j < 4; ++j)
                acc[i][j] = __builtin_amdgcn_mfma_f32_16x16x32_bf16(a[i], b[j], acc[i][j], 0, 0, 0);
        // NOTE: no second barrier needed. Next iter's writes hit buf[cur^1];
        // the prior reads of buf[cur^1] (iter t-1) were drained by the
        // compiler's lgkmcnt(0) before THIS iteration's barrier.
    }

    // ---- epilogue: C/D layout col = lane&15, row = (lane>>4)*4 + r (m89-verified)
    const int crow0 = bm * BM + wr * 64 + (lane >> 4) * 4;
    const int ccol0 = bn * BN + wc * 64 + fr;
#pragma unroll
    for (int i = 0; i < 4; ++i)
#pragma unroll
        for (int j = 0; j < 4; ++j)
#pragma unroll
            for (int r = 0; r < 4; ++r)
                C[(size_t)(crow0 + i * 16 + r) * N + (ccol0 + j * 16)] = acc[i][j][r];
}

extern "C" void kernel_launch(void* const* d_in, const int* in_sizes, int n_in,
                              void* d_out, int out_size, void* d_ws, size_t ws_size,
                              hipStream_t stream) {
    const int K = 4096;
    const int M = in_sizes[0] / K;   // 2048
    const int N = in_sizes[1] / K;   // 8192

    const float* x = (const float*)d_in[0];
    const float* w = (const float*)d_in[1];
    float* out     = (float*)d_out;

    const int nwg = (M / 128) * (N / 128);   // 1024
    gemm_bt_fused<<<dim3(nwg), dim3(256), 0, stream>>>(x, w, out, M, N, K);
}

// Round 4
// 265.337 us; speedup vs baseline: 1.1980x; 1.1980x over previous
//
#include <hip/hip_runtime.h>
#include <hip/hip_bf16.h>
#include <cstdint>

// out[M,N] = x[M,K] @ weight[N,K]^T, fp32 device buffers (fp16 reference ->
// harness float32 path). Single fused kernel (no d_ws; Round-2 lesson):
// fp32 global -> reg -> cvt bf16 -> XOR-swizzled double-buffered LDS ->
// 16x16x32 bf16 MFMA -> fp32 C.
// Round-4 changes vs Round-3:
//  (1) LDS XOR swizzle slot^=((row>>1)&3): kills the 8-way ds_read_b128
//      bank conflict (SQ_LDS_BANK_CONFLICT 3.36e7 -> ~free 2-way).
//  (2) bn-major block order in XCD chunks: 16 consecutive blocks share one
//      2MB B-panel (fits XCD L2); XCDs own disjoint bn ranges -> B fetched
//      ~once from HBM (FETCH_SIZE 1.09GB -> ~0.3GB predicted).

typedef __bf16 bf16x8 __attribute__((ext_vector_type(8)));
typedef float f32x4 __attribute__((ext_vector_type(4)));
typedef unsigned short u16x8 __attribute__((ext_vector_type(8)));

__device__ inline unsigned short f2bf(float f) {
    __hip_bfloat16 h = __float2bfloat16(f);  // RNE; compiler packs to v_cvt_pk_bf16_f32
    return *reinterpret_cast<unsigned short*>(&h);
}

// LDS offset (in shorts) of element (row, k): row*32 + swizzled 8-short slot.
// slot = k>>3 (four 16B slots per 64B row); swizzle spreads 16 consecutive
// rows' same-slot reads across all 32 banks (2-way aliasing = free, m136).
__device__ inline int lds_off(int row, int slot) {
    return row * 32 + (((slot ^ ((row >> 1) & 3)) & 3) << 3);
}

__global__ __launch_bounds__(256) void gemm_bt_fused(
    const float* __restrict__ A,   // x      [M,K]
    const float* __restrict__ B,   // weight [N,K]
    float* __restrict__ C,         // out    [M,N]
    int M, int N, int K)
{
    constexpr int BM = 128, BN = 128, BK = 32;
    __shared__ unsigned short sA[2][BM * BK];  // 2 x 8 KB
    __shared__ unsigned short sB[2][BN * BK];  // 2 x 8 KB

    const int nbm = M / BM;          // 16
    const int nbn = N / BN;          // 64
    const int nwg = nbm * nbn;       // 1024

    // XCD-chunked, bn-major mapping: XCD x owns swz in [x*q, (x+1)*q) ->
    // disjoint bn panels per XCD; 16 consecutive blocks share one B panel.
    const int bid = blockIdx.x;
    int swz = bid;
    if ((nwg & 7) == 0) {
        const int q = nwg >> 3;
        swz = (bid & 7) * q + (bid >> 3);
    }
    const int bm = swz % nbm;        // fast-varying: stream A panels
    const int bn = swz / nbm;        // slow-varying: B panel L2-resident

    const int tid = threadIdx.x;

    // ---- staging map: thread covers 16 contiguous floats of one tile row
    const int srow = tid >> 1;           // 0..127
    const int scol = (tid & 1) * 16;     // 0 or 16 (float index within row)
    const float* gA = A + (size_t)(bm * BM + srow) * K + scol;
    const float* gB = B + (size_t)(bn * BN + srow) * K + scol;
    const int s0   = (tid & 1) * 2;                // first 16B slot this thread fills
    const int wo0  = lds_off(srow, s0);            // swizzled write offsets (shorts)
    const int wo1  = lds_off(srow, s0 + 1);

    // ---- fragment geometry: wave (wr,wc) owns 64x64, acc[4][4] of 16x16
    const int wave = tid >> 6, lane = tid & 63;
    const int wr = wave >> 1, wc = wave & 1;
    const int fr = lane & 15;
    const int slr = lane >> 4;          // read slot = fk/8
    int offA[4], offB[4];
#pragma unroll
    for (int i = 0; i < 4; ++i) {
        offA[i] = lds_off(wr * 64 + i * 16 + fr, slr);
        offB[i] = lds_off(wc * 64 + i * 16 + fr, slr);
    }

    f32x4 acc[4][4] = {};
    const int NT = K / BK;               // 128

    // ---- prologue: load tile 0 into registers
    float4 va[4], vb[4];
#pragma unroll
    for (int p = 0; p < 4; ++p) {
        va[p] = *reinterpret_cast<const float4*>(gA + p * 4);
        vb[p] = *reinterpret_cast<const float4*>(gB + p * 4);
    }

    for (int t = 0; t < NT; ++t) {
        const int cur = t & 1;

        // convert current tile regs -> bf16, write to LDS buf[cur] (swizzled)
        u16x8 pa0, pa1, pb0, pb1;
#pragma unroll
        for (int e = 0; e < 4; ++e) {
            pa0[e]     = f2bf(va[0][e]);  pa0[4 + e] = f2bf(va[1][e]);
            pa1[e]     = f2bf(va[2][e]);  pa1[4 + e] = f2bf(va[3][e]);
            pb0[e]     = f2bf(vb[0][e]);  pb0[4 + e] = f2bf(vb[1][e]);
            pb1[e]     = f2bf(vb[2][e]);  pb1[4 + e] = f2bf(vb[3][e]);
        }
        *reinterpret_cast<u16x8*>(&sA[cur][wo0]) = pa0;
        *reinterpret_cast<u16x8*>(&sA[cur][wo1]) = pa1;
        *reinterpret_cast<u16x8*>(&sB[cur][wo0]) = pb0;
        *reinterpret_cast<u16x8*>(&sB[cur][wo1]) = pb1;

        // prefetch tile t+1 (clamped on last iter; redundant reload, harmless)
        const int kn = (t + 1 < NT) ? (t + 1) * BK : t * BK;
#pragma unroll
        for (int p = 0; p < 4; ++p) {
            va[p] = *reinterpret_cast<const float4*>(gA + kn + p * 4);
            vb[p] = *reinterpret_cast<const float4*>(gB + kn + p * 4);
        }

        __syncthreads();  // buf[cur] writes drained + all waves arrived

        bf16x8 a[4], b[4];
#pragma unroll
        for (int i = 0; i < 4; ++i) a[i] = *reinterpret_cast<const bf16x8*>(&sA[cur][offA[i]]);
#pragma unroll
        for (int j = 0; j < 4; ++j) b[j] = *reinterpret_cast<const bf16x8*>(&sB[cur][offB[j]]);
#pragma unroll
        for (int i = 0; i < 4; ++i)
#pragma unroll
            for (int j = 0; j < 4; ++j)
                acc[i][j] = __builtin_amdgcn_mfma_f32_16x16x32_bf16(a[i], b[j], acc[i][j], 0, 0, 0);
        // No second barrier: next iter writes buf[cur^1]; this iter's reads of
        // buf[cur] are drained by the compiler's lgkmcnt(0) before the NEXT
        // iteration's barrier, before buf[cur] is written again (t+2).
    }

    // ---- epilogue: C/D layout col = lane&15, row = (lane>>4)*4 + r (m89-verified)
    const int crow0 = bm * BM + wr * 64 + (lane >> 4) * 4;
    const int ccol0 = bn * BN + wc * 64 + fr;
#pragma unroll
    for (int i = 0; i < 4; ++i)
#pragma unroll
        for (int j = 0; j < 4; ++j)
#pragma unroll
            for (int r = 0; r < 4; ++r)
                C[(size_t)(crow0 + i * 16 + r) * N + (ccol0 + j * 16)] = acc[i][j][r];
}

extern "C" void kernel_launch(void* const* d_in, const int* in_sizes, int n_in,
                              void* d_out, int out_size, void* d_ws, size_t ws_size,
                              hipStream_t stream) {
    const int K = 4096;
    const int M = in_sizes[0] / K;   // 2048
    const int N = in_sizes[1] / K;   // 8192

    const float* x = (const float*)d_in[0];
    const float* w = (const float*)d_in[1];
    float* out     = (float*)d_out;

    const int nwg = (M / 128) * (N / 128);   // 1024
    gemm_bt_fused<<<dim3(nwg), dim3(256), 0, stream>>>(x, w, out, M, N, K);
}